// Round 3
// baseline (388.145 us; speedup 1.0000x reference)
//
#include <hip/hip_runtime.h>

typedef __bf16 bf16;
typedef __bf16 bf16x4 __attribute__((ext_vector_type(4)));
typedef __bf16 bf16x8 __attribute__((ext_vector_type(8)));
typedef float f32x4 __attribute__((ext_vector_type(4)));

#define CCH 128  // channels (all layers 128 -> 128)

// ---- prep: weights (O,I,K) fp32 -> MFMA-fragment-packed bf16 ----
// packed[((kt*4 + c)*8 + og)*512 + lane*8 + e], lane = quad*16 + m,
// o = og*16 + m, i = c*32 + quad*8 + e.
// => an A-fragment load for one wave is ONE contiguous 1KB burst.
__global__ void k_prep_wall(const float* __restrict__ w1, const float* __restrict__ w2,
                            const float* __restrict__ w3, const float* __restrict__ w4,
                            bf16* __restrict__ o1, bf16* __restrict__ o2,
                            bf16* __restrict__ o3, bf16* __restrict__ o4) {
    int idx = blockIdx.x * 256 + threadIdx.x;
    const float* src; bf16* dst; int Kw; int r = idx;
    if (r < 15 * 16384) { src = w1; dst = o1; Kw = 15; }
    else if ((r -= 15 * 16384) < 12 * 16384) { src = w2; dst = o2; Kw = 12; }
    else if ((r -= 12 * 16384) < 7 * 16384) { src = w3; dst = o3; Kw = 7; }
    else if ((r -= 7 * 16384) < 4 * 16384) { src = w4; dst = o4; Kw = 4; }
    else return;
    int e = r & 7, lane = (r >> 3) & 63, og = (r >> 9) & 7, c = (r >> 12) & 3, kt = r >> 14;
    int o = og * 16 + (lane & 15);
    int i = c * 32 + (lane >> 4) * 8 + e;
    dst[r] = (bf16)src[(o * 128 + i) * Kw + kt];
}

// ---- prep: centers fp32 -> bf16 [k][l(64, zero-pad l>=59)][o], plus ||c||^2 ----
__global__ void k_prep_c(const float* __restrict__ c, bf16* __restrict__ cbp,
                         float* __restrict__ cc) {
    int k = blockIdx.x;
    int tid = threadIdx.x;
    float s = 0.f;
    for (int idx = tid; idx < 64 * 128; idx += 256) {
        int l = idx >> 7;
        int o = idx & 127;
        float v = (l < 59) ? c[k * 7552 + o * 59 + l] : 0.f;
        bf16 b = (bf16)v;
        cbp[(size_t)k * 64 * 128 + idx] = b;
        float fv = (float)b;
        s += fv * fv;
    }
    __shared__ float red[256];
    red[tid] = s;
    __syncthreads();
    for (int st = 128; st > 0; st >>= 1) {
        if (tid < st) red[tid] += red[tid + st];
        __syncthreads();
    }
    if (tid == 0) cc[k] = red[0];
}

// ---- conv1, fused x transpose: reads x (N,C,1024) fp32 directly ----
// och-split wave partition (round-1 best); LT=64 so LDS=18.4KB -> 8 blocks/CU
// (32 waves/CU) with grid 2048: stage phases of some blocks overlap compute
// of others, hiding the barrier-drain latency.
__global__ __launch_bounds__(256, 8) void k_conv1(
    const float* __restrict__ x, const bf16* __restrict__ wTp,
    const float* __restrict__ bias, bf16* __restrict__ out) {
    constexpr int KW = 15, LT = 64, PH = 2, OUT_ROWS = 512;
    constexpr int P = (LT - 1) * 2 + KW;   // 141 input positions needed
    constexpr int KC = 2;                  // 32-chunks per phase
    constexpr int RS = 64;                 // LDS row stride (elems)
    constexpr int NLT = LT / 16;           // 4
    constexpr int NITS = (P + 15) / 16;    // 9 staging pos-blocks
    constexpr int PSTG = NITS * 16;        // 144 staged positions
    constexpr int ESE = 136;               // epilogue [l][o] stride
    constexpr int SMELE = (PSTG * RS > LT * ESE) ? PSTG * RS : LT * ESE;  // 9216
    constexpr int NJ = KW * KC;            // 30
    __shared__ __align__(16) bf16 smem[SMELE];

    const int n = blockIdx.y;
    const int l0 = blockIdx.x * LT;
    const int p0 = l0 * 2;
    const int tid = threadIdx.x;
    const int wid = tid >> 6;
    const int lane = tid & 63;
    const int quad = lane >> 4;
    const int l15 = lane & 15;
    const int og0 = wid * 2;               // wave owns o [wid*32, wid*32+32)

    f32x4 acc[2][NLT];
#pragma unroll
    for (int a = 0; a < 2; ++a)
#pragma unroll
        for (int b = 0; b < NLT; ++b) acc[a][b] = (f32x4){0.f, 0.f, 0.f, 0.f};

    bf16x8 afr[2][2];
    const bf16* wbase = wTp + (size_t)lane * 8;
    afr[0][0] = *(const bf16x8*)(wbase + ((size_t)(og0 + 0) << 9));
    afr[0][1] = *(const bf16x8*)(wbase + ((size_t)(og0 + 1) << 9));

    // staging decomposition: per iter, thread loads f32x4 of channel cst,
    // quad qw, position-block it. 4-lane groups read one 64B line.
    const int cst = tid >> 2;              // channel within phase (0..63)
    const int qw = tid & 3;                // quad within 16-pos block

#pragma unroll 1
    for (int ph = 0; ph < PH; ++ph) {
        if (ph) __syncthreads();  // protect smem against overwrite

        const float* bch = x + ((size_t)(n * 128 + ph * 64 + cst)) * 1024;
#pragma unroll 3
        for (int it = 0; it < NITS; ++it) {
            int pp = it * 16 + qw * 4;
            int gp = p0 + pp;
            f32x4 t;
            if (gp + 3 < 1024) {
                t = *(const f32x4*)(bch + gp);
            } else {
#pragma unroll
                for (int e = 0; e < 4; ++e) t[e] = (gp + e < 1024) ? bch[gp + e] : 0.f;
            }
#pragma unroll
            for (int e = 0; e < 4; ++e) {
                int ppe = pp + e;
                int sc8 = (((cst >> 3) ^ ((ppe >> 1) & 7)) << 3) | (cst & 7);
                smem[ppe * RS + sc8] = (bf16)t[e];
            }
        }
        __syncthreads();

#pragma unroll 2
        for (int j = 0; j < NJ; ++j) {
            int nj = j + 1, nph = ph;
            if (nj == NJ) { nj = 0; ++nph; }
            if (nph < PH) {
                int kt1 = nj >> 1;
                int c1 = (nj & (KC - 1)) + nph * KC;
                const bf16* wp = wbase + ((size_t)((kt1 * 4 + c1) * 8 + og0) << 9);
                afr[(j + 1) & 1][0] = *(const bf16x8*)(wp);
                afr[(j + 1) & 1][1] = *(const bf16x8*)(wp + 512);
            }
            const int kt = j >> 1;
            const int c16l = (j & (KC - 1)) * 4 + quad;
#pragma unroll
            for (int lt = 0; lt < NLT; ++lt) {
                int p = (lt * 16 + l15) * 2 + kt;
                int sc = c16l ^ ((p >> 1) & 7);
                bf16x8 bfr = *(const bf16x8*)(smem + p * RS + sc * 8);
                acc[0][lt] = __builtin_amdgcn_mfma_f32_16x16x32_bf16(
                    afr[j & 1][0], bfr, acc[0][lt], 0, 0, 0);
                acc[1][lt] = __builtin_amdgcn_mfma_f32_16x16x32_bf16(
                    afr[j & 1][1], bfr, acc[1][lt], 0, 0, 0);
            }
        }
    }

    // ---- epilogue: bias+act -> LDS [l][o] -> contiguous 16B stores ----
    __syncthreads();
#pragma unroll
    for (int ot = 0; ot < 2; ++ot) {
        const int o0 = wid * 32 + ot * 16 + quad * 4;
        const f32x4 bv = *(const f32x4*)(bias + o0);
#pragma unroll
        for (int lt = 0; lt < NLT; ++lt) {
            const int l = lt * 16 + l15;
            bf16x4 pk;
#pragma unroll
            for (int r = 0; r < 4; ++r) {
                float v = acc[ot][lt][r] + bv[r];
                v = (v > 0.f) ? v : 0.1f * v;
                pk[r] = (bf16)v;
            }
            *(bf16x4*)(smem + l * ESE + o0) = pk;
        }
    }
    __syncthreads();
    constexpr int SNIT = LT * 16 / 256;
    bf16* op = out + ((size_t)n * OUT_ROWS + l0) * CCH;
#pragma unroll
    for (int it = 0; it < SNIT; ++it) {
        int u = tid + it * 256;
        int l = u >> 4;
        int g = u & 15;
        *(bf16x8*)(op + l * CCH + g * 8) = *(const bf16x8*)(smem + l * ESE + g * 8);
    }
}

// ---- conv layer: implicit GEMM, bf16 MFMA, position-major both sides ----
// och-split wave partition; small LT => 8 blocks/CU for latency hiding.
template <int KW, int IN_CAP, int OUT_ROWS, int LT, int PH, bool ACT>
__global__ __launch_bounds__(256, 8) void k_conv(
    const bf16* __restrict__ in_, const bf16* __restrict__ wTp,
    const float* __restrict__ bias, bf16* __restrict__ out) {
    constexpr int P = (LT - 1) * 2 + KW;   // input positions needed
    constexpr int CPP = 128 / PH;          // channels per phase
    constexpr int KC = CPP / 32;           // 32-chunks per phase
    constexpr int C16N = CPP / 8;          // 16B chunks per phase
    constexpr int RS = CPP;                // LDS row stride (elems)
    constexpr int KCL = (KC == 4) ? 2 : 1;
    constexpr int NLT = LT / 16;
    constexpr int ESE = 136;               // epilogue [l][o] stride
    constexpr int SMELE = (P * RS > LT * ESE) ? P * RS : LT * ESE;
    constexpr int NJ = KW * KC;
    __shared__ __align__(16) bf16 smem[SMELE];

    const int n = blockIdx.y;
    const int l0 = blockIdx.x * LT;
    const int p0 = l0 * 2;
    const int tid = threadIdx.x;
    const int wid = tid >> 6;
    const int lane = tid & 63;
    const int quad = lane >> 4;
    const int l15 = lane & 15;
    const int og0 = wid * 2;               // wave owns o [wid*32, wid*32+32)

    f32x4 acc[2][NLT];
#pragma unroll
    for (int a = 0; a < 2; ++a)
#pragma unroll
        for (int b = 0; b < NLT; ++b) acc[a][b] = (f32x4){0.f, 0.f, 0.f, 0.f};

    bf16x8 afr[2][2];
    const bf16* wbase = wTp + (size_t)lane * 8;

    afr[0][0] = *(const bf16x8*)(wbase + ((size_t)(og0 + 0) << 9));
    afr[0][1] = *(const bf16x8*)(wbase + ((size_t)(og0 + 1) << 9));

#pragma unroll 1
    for (int ph = 0; ph < PH; ++ph) {
        if (ph) __syncthreads();  // protect smem against overwrite

        constexpr int UNITS = P * C16N;
        constexpr int NIT = (UNITS + 255) / 256;
        const bf16* base = in_ + ((size_t)n * IN_CAP + p0) * CCH + ph * CPP;
#pragma unroll
        for (int it = 0; it < NIT; ++it) {
            int u = tid + it * 256;
            if ((UNITS & 255) == 0 || u < UNITS) {
                int p = u >> ((C16N == 16) ? 4 : 3);
                int c = u & (C16N - 1);
                bf16x8 t = *(const bf16x8*)(base + (size_t)p * CCH + c * 8);
                int sc = (PH == 2) ? (c ^ ((p >> 1) & 7))
                                   : ((c & 8) | ((c & 7) ^ ((p >> 1) & 7)));
                *(bf16x8*)(smem + p * RS + sc * 8) = t;
            }
        }
        __syncthreads();

#pragma unroll 2
        for (int j = 0; j < NJ; ++j) {
            int nj = j + 1, nph = ph;
            if (nj == NJ) { nj = 0; ++nph; }
            if (nph < PH) {
                int kt1 = nj >> KCL;
                int c1 = (nj & (KC - 1)) + nph * KC;
                const bf16* wp = wbase + ((size_t)((kt1 * 4 + c1) * 8 + og0) << 9);
                afr[(j + 1) & 1][0] = *(const bf16x8*)(wp);
                afr[(j + 1) & 1][1] = *(const bf16x8*)(wp + 512);
            }
            const int kt = j >> KCL;
            const int c16l = (j & (KC - 1)) * 4 + quad;
#pragma unroll
            for (int lt = 0; lt < NLT; ++lt) {
                int p = (lt * 16 + l15) * 2 + kt;
                int sc = (PH == 2) ? (c16l ^ ((p >> 1) & 7))
                                   : ((c16l & 8) | ((c16l & 7) ^ ((p >> 1) & 7)));
                bf16x8 bfr = *(const bf16x8*)(smem + p * RS + sc * 8);
                acc[0][lt] = __builtin_amdgcn_mfma_f32_16x16x32_bf16(
                    afr[j & 1][0], bfr, acc[0][lt], 0, 0, 0);
                acc[1][lt] = __builtin_amdgcn_mfma_f32_16x16x32_bf16(
                    afr[j & 1][1], bfr, acc[1][lt], 0, 0, 0);
            }
        }
    }

    // ---- epilogue: bias+act -> LDS [l][o] -> contiguous 16B stores ----
    __syncthreads();
#pragma unroll
    for (int ot = 0; ot < 2; ++ot) {
        const int o0 = wid * 32 + ot * 16 + quad * 4;
        const f32x4 bv = *(const f32x4*)(bias + o0);
#pragma unroll
        for (int lt = 0; lt < NLT; ++lt) {
            const int l = lt * 16 + l15;
            bf16x4 pk;
#pragma unroll
            for (int r = 0; r < 4; ++r) {
                float v = acc[ot][lt][r] + bv[r];
                if (ACT) v = (v > 0.f) ? v : 0.1f * v;
                pk[r] = (bf16)v;
            }
            *(bf16x4*)(smem + l * ESE + o0) = pk;
        }
    }
    __syncthreads();
    constexpr int SNIT = LT * 16 / 256;
    bf16* op = out + ((size_t)n * OUT_ROWS + l0) * CCH;
#pragma unroll
    for (int it = 0; it < SNIT; ++it) {
        int u = tid + it * 256;
        int l = u >> 4;
        int g = u & 15;
        *(bf16x8*)(op + l * CCH + g * 8) = *(const bf16x8*)(smem + l * ESE + g * 8);
    }
}

// ---- fused conv4 + distances + Student-t assignment (one block per n) ----
// 512 threads (2 waves/SIMD). conv4: 8 waves x (16o x 64l). Dist: per pass,
// each wave owns one center; cbp reads are lane-contiguous 1KB bursts;
// shuffle allreduce per center.
__global__ __launch_bounds__(512, 1) void k_conv4_dist(
    const bf16* __restrict__ in_, const bf16* __restrict__ wTp,
    const float* __restrict__ bias, const bf16* __restrict__ cbp,
    const float* __restrict__ cc, float* __restrict__ out) {
    constexpr int P = 130, NJ = 16;
    constexpr int ESE = 136;
    __shared__ __align__(16) bf16 smem[P * 128];
    __shared__ __align__(16) bf16 zmem[64 * ESE];
    __shared__ float d2s[64];

    const int n = blockIdx.x;
    const int tid = threadIdx.x;
    const int wid = tid >> 6;     // 0..7
    const int lane = tid & 63;
    const int quad = lane >> 4;
    const int l15 = lane & 15;

    f32x4 acc[4];
#pragma unroll
    for (int b = 0; b < 4; ++b) acc[b] = (f32x4){0.f, 0.f, 0.f, 0.f};

    bf16x8 afr[2];
    const bf16* wbase = wTp + (size_t)lane * 8;
    afr[0] = *(const bf16x8*)(wbase + ((size_t)wid << 9));  // kt=0,c=0,og=wid

    {
        constexpr int UNITS = P * 16;  // 2080
        const bf16* base = in_ + (size_t)n * 128 * CCH;
#pragma unroll
        for (int it = 0; it < 5; ++it) {
            int u = tid + it * 512;
            if (u < UNITS) {
                int p = u >> 4;
                int c = u & 15;
                bf16x8 t = *(const bf16x8*)(base + (size_t)p * CCH + c * 8);
                int sc = (c & 8) | ((c & 7) ^ ((p >> 1) & 7));
                *(bf16x8*)(smem + p * 128 + sc * 8) = t;
            }
        }
    }
    __syncthreads();

#pragma unroll 2
    for (int j = 0; j < NJ; ++j) {
        if (j + 1 < NJ) {
            int kt1 = (j + 1) >> 2;
            int c1 = (j + 1) & 3;
            afr[(j + 1) & 1] =
                *(const bf16x8*)(wbase + ((size_t)((kt1 * 4 + c1) * 8 + wid) << 9));
        }
        const int kt = j >> 2;
        const int c16l = (j & 3) * 4 + quad;
#pragma unroll
        for (int lt = 0; lt < 4; ++lt) {
            int p = (lt * 16 + l15) * 2 + kt;
            int sc = (c16l & 8) | ((c16l & 7) ^ ((p >> 1) & 7));
            bf16x8 bfr = *(const bf16x8*)(smem + p * 128 + sc * 8);
            acc[lt] = __builtin_amdgcn_mfma_f32_16x16x32_bf16(afr[j & 1], bfr, acc[lt], 0, 0, 0);
        }
    }

    // epilogue -> z bf16 [l][o], zeros l>=59 (pads match zero-padded centers)
    {
        const int o0 = wid * 16 + quad * 4;
        const f32x4 bv = *(const f32x4*)(bias + o0);
#pragma unroll
        for (int lt = 0; lt < 4; ++lt) {
            const int l = lt * 16 + l15;
            bf16x4 pk;
#pragma unroll
            for (int r = 0; r < 4; ++r) {
                float v = acc[lt][r] + bv[r];
                pk[r] = (l < 59) ? (bf16)v : (bf16)0.f;
            }
            *(bf16x4*)(zmem + l * ESE + o0) = pk;
        }
    }
    __syncthreads();

    // dist: 8 passes, wave wid owns center kc = cp*8 + wid.
    // cbp row reads: lane-contiguous 1KB per instruction (fully coalesced).
#pragma unroll 1
    for (int cp = 0; cp < 8; ++cp) {
        const int kc = cp * 8 + wid;
        const bf16* cr = cbp + (size_t)kc * 8192;
        float t = 0.f;
#pragma unroll
        for (int it = 0; it < 16; ++it) {
            int ci = it * 64 + lane;
            int l = ci >> 4;
            int g = ci & 15;
            bf16x8 cv = *(const bf16x8*)(cr + ci * 8);
            bf16x8 zv = *(const bf16x8*)(zmem + l * ESE + g * 8);
#pragma unroll
            for (int e = 0; e < 8; ++e) {
                float zf = (float)zv[e];
                t += zf * (zf - 2.f * (float)cv[e]);
            }
        }
#pragma unroll
        for (int o = 32; o > 0; o >>= 1) t += __shfl_xor(t, o);
        if (lane == 0) d2s[kc] = t + cc[kc];
    }
    __syncthreads();
    if (tid < 64) {
        float q = 1.f / (1.f + d2s[tid]);  // ALPHA=1, exponent (ALPHA+1)/2 == 1
        float tot = q;
#pragma unroll
        for (int o = 32; o > 0; o >>= 1) tot += __shfl_xor(tot, o);
        out[n * 64 + tid] = q / tot;
    }
}

// ---------------- launcher ----------------
extern "C" void kernel_launch(void* const* d_in, const int* in_sizes, int n_in,
                              void* d_out, int out_size, void* d_ws, size_t ws_size,
                              hipStream_t stream) {
    (void)in_sizes; (void)n_in; (void)out_size; (void)ws_size;
    const float* x   = (const float*)d_in[0];
    const float* w1  = (const float*)d_in[1];
    const float* b1  = (const float*)d_in[2];
    const float* w2  = (const float*)d_in[3];
    const float* b2  = (const float*)d_in[4];
    const float* w3  = (const float*)d_in[5];
    const float* b3  = (const float*)d_in[6];
    const float* w4  = (const float*)d_in[7];
    const float* b4  = (const float*)d_in[8];
    const float* cen = (const float*)d_in[9];
    float* out = (float*)d_out;

    char* ws = (char*)d_ws;
    size_t off = 0;
    auto alloc = [&](size_t bytes) -> void* {
        void* p = ws + off;
        off += (bytes + 255) & ~(size_t)255;
        return p;
    };
    bf16* wT1 = (bf16*)alloc((size_t)15 * 16384 * sizeof(bf16));
    bf16* wT2 = (bf16*)alloc((size_t)12 * 16384 * sizeof(bf16));
    bf16* wT3 = (bf16*)alloc((size_t)7 * 16384 * sizeof(bf16));
    bf16* wT4 = (bf16*)alloc((size_t)4 * 16384 * sizeof(bf16));
    bf16* cbp = (bf16*)alloc((size_t)64 * 64 * 128 * sizeof(bf16));
    float* cc = (float*)alloc(64 * sizeof(float));
    // position-major intermediates [n][row][128]; conv1 reads x directly
    // (fp32->bf16 transpose fused into its staging), so no xT buffer.
    bf16* h1  = (bf16*)alloc((size_t)256 * 512 * 128 * sizeof(bf16));
    bf16* h2  = (bf16*)alloc((size_t)256 * 256 * 128 * sizeof(bf16));
    bf16* h3  = h1;   // reuse: h1 dead after conv2
    (void)alloc((size_t)1 << 20);  // slack: tile overreads stay in-bounds

    k_prep_wall<<<(38 * 16384 + 255) / 256, 256, 0, stream>>>(w1, w2, w3, w4, wT1, wT2, wT3, wT4);
    k_prep_c<<<64, 256, 0, stream>>>(cen, cbp, cc);

    // conv1 (fused transpose): x 1024 -> 505(512 rows) K=15, LeakyReLU; LT=64
    k_conv1<<<dim3(8, 256), 256, 0, stream>>>(x, wT1, b1, h1);
    // conv2: 505 -> 247(256 rows) K=12, LeakyReLU; LT=32 -> 2048 blocks
    k_conv<12, 512, 256, 32, 1, true>
        <<<dim3(8, 256), 256, 0, stream>>>(h1, wT2, b2, h2);
    // conv3: 247 -> 121(128 rows) K=7, LeakyReLU; LT=16 -> 2048 blocks
    k_conv<7, 256, 128, 16, 1, true>
        <<<dim3(8, 256), 256, 0, stream>>>(h2, wT3, b3, h3);
    // conv4 (121 -> 59, K=4) fused with distances + softmax-normalize; 512 thr
    k_conv4_dist<<<256, 512, 0, stream>>>(h3, wT4, b4, cbp, cc, out);
}

// Round 5
// 312.431 us; speedup vs baseline: 1.2423x; 1.2423x over previous
//
#include <hip/hip_runtime.h>

typedef __bf16 bf16;
typedef __bf16 bf16x4 __attribute__((ext_vector_type(4)));
typedef __bf16 bf16x8 __attribute__((ext_vector_type(8)));
typedef float f32x4 __attribute__((ext_vector_type(4)));

#define CCH 128  // channels (all layers 128 -> 128)

// ---- prep (merged): weights (O,I,K) fp32 -> MFMA-packed bf16; centers ----
// packed[((kt*4 + c)*8 + og)*512 + lane*8 + e], o = og*16 + (lane&15),
// i = c*32 + (lane>>4)*8 + e  => A-fragment load = one contiguous 1KB burst.
__global__ void k_prep_all(const float* __restrict__ w1, const float* __restrict__ w2,
                           const float* __restrict__ w3, const float* __restrict__ w4,
                           const float* __restrict__ cen,
                           bf16* __restrict__ o1, bf16* __restrict__ o2,
                           bf16* __restrict__ o3, bf16* __restrict__ o4,
                           bf16* __restrict__ cbp, float* __restrict__ cc) {
    __shared__ float red[256];
    int tid = threadIdx.x;
    if (blockIdx.x < 2432) {
        int idx = blockIdx.x * 256 + tid;
        const float* src; bf16* dst; int Kw; int r = idx;
        if (r < 15 * 16384) { src = w1; dst = o1; Kw = 15; }
        else if ((r -= 15 * 16384) < 12 * 16384) { src = w2; dst = o2; Kw = 12; }
        else if ((r -= 12 * 16384) < 7 * 16384) { src = w3; dst = o3; Kw = 7; }
        else if ((r -= 7 * 16384) < 4 * 16384) { src = w4; dst = o4; Kw = 4; }
        else return;
        int e = r & 7, lane = (r >> 3) & 63, og = (r >> 9) & 7, c = (r >> 12) & 3, kt = r >> 14;
        int o = og * 16 + (lane & 15);
        int i = c * 32 + (lane >> 4) * 8 + e;
        dst[r] = (bf16)src[(o * 128 + i) * Kw + kt];
    } else {
        // centers fp32 -> bf16 [k][l(64, zero-pad l>=59)][o], plus ||c||^2
        int k = blockIdx.x - 2432;
        float s = 0.f;
        for (int idx = tid; idx < 64 * 128; idx += 256) {
            int l = idx >> 7;
            int o = idx & 127;
            float v = (l < 59) ? cen[k * 7552 + o * 59 + l] : 0.f;
            bf16 b = (bf16)v;
            cbp[(size_t)k * 64 * 128 + idx] = b;
            float fv = (float)b;
            s += fv * fv;
        }
        red[tid] = s;
        __syncthreads();
        for (int st = 128; st > 0; st >>= 1) {
            if (tid < st) red[tid] += red[tid + st];
            __syncthreads();
        }
        if (tid == 0) cc[k] = red[0];
    }
}

// ---- conv1, fused x transpose (round-1 best config, unchanged) ----
__global__ __launch_bounds__(256, 4) void k_conv1(
    const float* __restrict__ x, const bf16* __restrict__ wTp,
    const float* __restrict__ bias, bf16* __restrict__ out) {
    constexpr int KW = 15, LT = 128, PH = 2, OUT_ROWS = 512;
    constexpr int P = (LT - 1) * 2 + KW;   // 269 input positions needed
    constexpr int KC = 2;                  // 32-chunks per phase
    constexpr int RS = 64;                 // LDS row stride (elems)
    constexpr int NLT = LT / 16;           // 8
    constexpr int ESE = 136;               // epilogue [l][o] stride
    constexpr int SMELE = (P * RS > LT * ESE) ? P * RS : LT * ESE;  // 17408
    constexpr int NJ = KW * KC;            // 30
    __shared__ __align__(16) bf16 smem[SMELE];

    const int n = blockIdx.y;
    const int l0 = blockIdx.x * LT;
    const int p0 = l0 * 2;
    const int tid = threadIdx.x;
    const int wid = tid >> 6;
    const int lane = tid & 63;
    const int quad = lane >> 4;
    const int l15 = lane & 15;
    const int og0 = wid * 2;               // wave owns o [wid*32, wid*32+32)

    f32x4 acc[2][NLT];
#pragma unroll
    for (int a = 0; a < 2; ++a)
#pragma unroll
        for (int b = 0; b < NLT; ++b) acc[a][b] = (f32x4){0.f, 0.f, 0.f, 0.f};

    bf16x8 afr[2][2];
    const bf16* wbase = wTp + (size_t)lane * 8;
    afr[0][0] = *(const bf16x8*)(wbase + ((size_t)(og0 + 0) << 9));
    afr[0][1] = *(const bf16x8*)(wbase + ((size_t)(og0 + 1) << 9));

    const int cst = tid >> 2;              // channel within phase (0..63)
    const int qw = tid & 3;                // quad within 16-pos block

#pragma unroll 1
    for (int ph = 0; ph < PH; ++ph) {
        if (ph) __syncthreads();  // protect smem against overwrite

        const float* bch = x + ((size_t)(n * 128 + ph * 64 + cst)) * 1024;
#pragma unroll 4
        for (int it = 0; it < 17; ++it) {   // 17*16 = 272 positions (>=269)
            int pp = it * 16 + qw * 4;
            int gp = p0 + pp;
            f32x4 t;
            if (gp + 3 < 1024) {
                t = *(const f32x4*)(bch + gp);
            } else {
#pragma unroll
                for (int e = 0; e < 4; ++e) t[e] = (gp + e < 1024) ? bch[gp + e] : 0.f;
            }
#pragma unroll
            for (int e = 0; e < 4; ++e) {
                int ppe = pp + e;
                int sc8 = (((cst >> 3) ^ ((ppe >> 1) & 7)) << 3) | (cst & 7);
                smem[ppe * RS + sc8] = (bf16)t[e];
            }
        }
        __syncthreads();

#pragma unroll 2
        for (int j = 0; j < NJ; ++j) {
            int nj = j + 1, nph = ph;
            if (nj == NJ) { nj = 0; ++nph; }
            if (nph < PH) {
                int kt1 = nj >> 1;
                int c1 = (nj & (KC - 1)) + nph * KC;
                const bf16* wp = wbase + ((size_t)((kt1 * 4 + c1) * 8 + og0) << 9);
                afr[(j + 1) & 1][0] = *(const bf16x8*)(wp);
                afr[(j + 1) & 1][1] = *(const bf16x8*)(wp + 512);
            }
            const int kt = j >> 1;
            const int c16l = (j & (KC - 1)) * 4 + quad;
#pragma unroll
            for (int lt = 0; lt < NLT; ++lt) {
                int p = (lt * 16 + l15) * 2 + kt;
                int sc = c16l ^ ((p >> 1) & 7);
                bf16x8 bfr = *(const bf16x8*)(smem + p * RS + sc * 8);
                acc[0][lt] = __builtin_amdgcn_mfma_f32_16x16x32_bf16(
                    afr[j & 1][0], bfr, acc[0][lt], 0, 0, 0);
                acc[1][lt] = __builtin_amdgcn_mfma_f32_16x16x32_bf16(
                    afr[j & 1][1], bfr, acc[1][lt], 0, 0, 0);
            }
        }
    }

    __syncthreads();
#pragma unroll
    for (int ot = 0; ot < 2; ++ot) {
        const int o0 = wid * 32 + ot * 16 + quad * 4;
        const f32x4 bv = *(const f32x4*)(bias + o0);
#pragma unroll
        for (int lt = 0; lt < NLT; ++lt) {
            const int l = lt * 16 + l15;
            bf16x4 pk;
#pragma unroll
            for (int r = 0; r < 4; ++r) {
                float v = acc[ot][lt][r] + bv[r];
                v = (v > 0.f) ? v : 0.1f * v;
                pk[r] = (bf16)v;
            }
            *(bf16x4*)(smem + l * ESE + o0) = pk;
        }
    }
    __syncthreads();
    constexpr int SNIT = LT * 16 / 256;
    bf16* op = out + ((size_t)n * OUT_ROWS + l0) * CCH;
#pragma unroll
    for (int it = 0; it < SNIT; ++it) {
        int u = tid + it * 256;
        int l = u >> 4;
        int g = u & 15;
        *(bf16x8*)(op + l * CCH + g * 8) = *(const bf16x8*)(smem + l * ESE + g * 8);
    }
}

// ---- fused conv2+conv3+conv4+distances: ONE block per n, 512 threads ----
// h2/h3 live entirely in LDS; every epilogue writes the XOR-swizzled layout
// the next layer's MFMA B-reads expect. conv2 input staged from global h1
// via the proven register-staged global->reg->swizzled ds_write pattern.
__global__ __launch_bounds__(512, 1) void k_fused234(
    const bf16* __restrict__ h1g, const bf16* __restrict__ wT2,
    const bf16* __restrict__ wT3, const bf16* __restrict__ wT4,
    const float* __restrict__ b2, const float* __restrict__ b3,
    const float* __restrict__ b4, const bf16* __restrict__ cbp,
    const float* __restrict__ cc, float* __restrict__ out) {
    // LDS plan (bf16 elems):
    //  region A (34048 el = 68KB): sbuf 266 rows x128 during conv2;
    //                              then h3 (130 rows x128 = 16640) + zmem (64x136)
    //  region B (33536 el = 67KB): h2 262 rows x128 (rows 256.. zero-initialized)
    __shared__ __align__(16) bf16 lds[34048 + 33536];
    __shared__ float d2s[64];
    bf16* sbuf = lds;
    bf16* h2   = lds + 34048;
    bf16* h3   = lds;           // after conv2
    bf16* zmem = lds + 16640;   // after conv2

    const int n = blockIdx.x;
    const int tid = threadIdx.x;
    const int wid = tid >> 6;     // 0..7
    const int lane = tid & 63;
    const int quad = lane >> 4;
    const int l15 = lane & 15;

    // zero junk h2 rows 256..261 (read by conv3 tail, never written)
    if (tid < 96) *(f32x4*)(h2 + 256 * 128 + tid * 8) = (f32x4){0.f, 0.f, 0.f, 0.f};

    // ================= conv2: h1(global) -> h2(LDS), K=12, LeakyReLU ======
    // two 64-row tiles computed concurrently per stage: wavegroup g=wid>>2
    // owns tile 2s+g; within group: w4=wid&3 -> og pair, all 64 rows (NLT=4).
    {
        const int w4 = wid & 3;
        const int g = wid >> 2;
        const int og0 = w4 * 2;
        const bf16* w2base = wT2 + (size_t)lane * 8;
        constexpr int NJ2 = 48;                 // 12 kt x 4 c
#pragma unroll 1
        for (int s = 0; s < 2; ++s) {
            if (s) __syncthreads();
            // stage h1 rows [s*256, s*256+266) -> sbuf (local rows 0..265),
            // write-side XOR swizzle (same pattern as k_conv staging)
            {
                const bf16* base = h1g + (size_t)n * 512 * 128;
#pragma unroll
                for (int it = 0; it < 9; ++it) {
                    int u = tid + it * 512;
                    if (u < 266 * 16) {
                        int p = u >> 4, c = u & 15;
                        int prow = s * 256 + p; if (prow > 511) prow = 511;
                        bf16x8 t = *(const bf16x8*)(base + (size_t)prow * 128 + c * 8);
                        int sc = (c & 8) | ((c & 7) ^ ((p >> 1) & 7));
                        *(bf16x8*)(sbuf + p * 128 + sc * 8) = t;
                    }
                }
            }
            __syncthreads();

            f32x4 acc[2][4];
#pragma unroll
            for (int a = 0; a < 2; ++a)
#pragma unroll
                for (int b = 0; b < 4; ++b) acc[a][b] = (f32x4){0.f, 0.f, 0.f, 0.f};
            bf16x8 afr[2][2];
            afr[0][0] = *(const bf16x8*)(w2base + ((size_t)og0 << 9));
            afr[0][1] = *(const bf16x8*)(w2base + ((size_t)(og0 + 1) << 9));
#pragma unroll 2
            for (int j = 0; j < NJ2; ++j) {
                if (j + 1 < NJ2) {
                    int kt1 = (j + 1) >> 2, c1 = (j + 1) & 3;
                    const bf16* wp = w2base + ((size_t)((kt1 * 4 + c1) * 8 + og0) << 9);
                    afr[(j + 1) & 1][0] = *(const bf16x8*)(wp);
                    afr[(j + 1) & 1][1] = *(const bf16x8*)(wp + 512);
                }
                int kt = j >> 2;
                int c16l = (j & 3) * 4 + quad;
#pragma unroll
                for (int lt = 0; lt < 4; ++lt) {
                    int p = (g * 64 + lt * 16 + l15) * 2 + kt;   // local sbuf row
                    int sc = (c16l & 8) | ((c16l & 7) ^ ((p >> 1) & 7));
                    bf16x8 bfr = *(const bf16x8*)(sbuf + p * 128 + sc * 8);
                    acc[0][lt] = __builtin_amdgcn_mfma_f32_16x16x32_bf16(
                        afr[j & 1][0], bfr, acc[0][lt], 0, 0, 0);
                    acc[1][lt] = __builtin_amdgcn_mfma_f32_16x16x32_bf16(
                        afr[j & 1][1], bfr, acc[1][lt], 0, 0, 0);
                }
            }
            // epilogue -> h2 (swizzled layout conv3 expects), LeakyReLU
#pragma unroll
            for (int ot = 0; ot < 2; ++ot) {
                int o0 = (og0 + ot) * 16 + quad * 4;
                f32x4 bv = *(const f32x4*)(b2 + o0);
                int c = o0 >> 3;
#pragma unroll
                for (int lt = 0; lt < 4; ++lt) {
                    int l = s * 128 + g * 64 + lt * 16 + l15;   // h2 row 0..255
                    bf16x4 pk;
#pragma unroll
                    for (int r = 0; r < 4; ++r) {
                        float v = acc[ot][lt][r] + bv[r];
                        v = (v > 0.f) ? v : 0.1f * v;
                        pk[r] = (bf16)v;
                    }
                    int sc = (c & 8) | ((c & 7) ^ ((l >> 1) & 7));
                    *(bf16x4*)(h2 + l * 128 + sc * 8 + (o0 & 7)) = pk;
                }
            }
            __syncthreads();
        }
    }

    // ================= conv3: h2(LDS) -> h3(LDS), K=7, LeakyReLU ==========
    {
        // zero junk h3 rows 128..129 (read by conv4 tail)
        if (tid < 32) *(f32x4*)(h3 + 128 * 128 + tid * 8) = (f32x4){0.f, 0.f, 0.f, 0.f};
        const int og0 = (wid & 3) * 2;
        const int ph3 = wid >> 2;            // 64-row half
        const bf16* w3base = wT3 + (size_t)lane * 8;
        constexpr int NJ3 = 28;              // 7 kt x 4 c
        f32x4 acc[2][4];
#pragma unroll
        for (int a = 0; a < 2; ++a)
#pragma unroll
            for (int b = 0; b < 4; ++b) acc[a][b] = (f32x4){0.f, 0.f, 0.f, 0.f};
        bf16x8 afr[2][2];
        afr[0][0] = *(const bf16x8*)(w3base + ((size_t)og0 << 9));
        afr[0][1] = *(const bf16x8*)(w3base + ((size_t)(og0 + 1) << 9));
#pragma unroll 2
        for (int j = 0; j < NJ3; ++j) {
            if (j + 1 < NJ3) {
                int kt1 = (j + 1) >> 2, c1 = (j + 1) & 3;
                const bf16* wp = w3base + ((size_t)((kt1 * 4 + c1) * 8 + og0) << 9);
                afr[(j + 1) & 1][0] = *(const bf16x8*)(wp);
                afr[(j + 1) & 1][1] = *(const bf16x8*)(wp + 512);
            }
            int kt = j >> 2;
            int c16l = (j & 3) * 4 + quad;
#pragma unroll
            for (int lt = 0; lt < 4; ++lt) {
                int p = (ph3 * 64 + lt * 16 + l15) * 2 + kt;   // h2 row <= 260
                int sc = (c16l & 8) | ((c16l & 7) ^ ((p >> 1) & 7));
                bf16x8 bfr = *(const bf16x8*)(h2 + p * 128 + sc * 8);
                acc[0][lt] = __builtin_amdgcn_mfma_f32_16x16x32_bf16(
                    afr[j & 1][0], bfr, acc[0][lt], 0, 0, 0);
                acc[1][lt] = __builtin_amdgcn_mfma_f32_16x16x32_bf16(
                    afr[j & 1][1], bfr, acc[1][lt], 0, 0, 0);
            }
        }
        __syncthreads();   // sbuf (region A) dead; safe to write h3
        // epilogue -> h3 (swizzled layout conv4 expects), LeakyReLU
#pragma unroll
        for (int ot = 0; ot < 2; ++ot) {
            int o0 = (og0 + ot) * 16 + quad * 4;
            f32x4 bv = *(const f32x4*)(b3 + o0);
            int c = o0 >> 3;
#pragma unroll
            for (int lt = 0; lt < 4; ++lt) {
                int l = ph3 * 64 + lt * 16 + l15;   // h3 row 0..127
                bf16x4 pk;
#pragma unroll
                for (int r = 0; r < 4; ++r) {
                    float v = acc[ot][lt][r] + bv[r];
                    v = (v > 0.f) ? v : 0.1f * v;
                    pk[r] = (bf16)v;
                }
                int sc = (c & 8) | ((c & 7) ^ ((l >> 1) & 7));
                *(bf16x4*)(h3 + l * 128 + sc * 8 + (o0 & 7)) = pk;
            }
        }
    }
    __syncthreads();

    // ================= conv4: h3(LDS) -> zmem, no act, zero-pad l>=59 =====
    {
        f32x4 acc[4];
#pragma unroll
        for (int b = 0; b < 4; ++b) acc[b] = (f32x4){0.f, 0.f, 0.f, 0.f};
        bf16x8 afr[2];
        const bf16* w4base = wT4 + (size_t)lane * 8;
        afr[0] = *(const bf16x8*)(w4base + ((size_t)wid << 9));  // kt=0,c=0,og=wid
        constexpr int NJ4 = 16;              // 4 kt x 4 c
#pragma unroll 2
        for (int j = 0; j < NJ4; ++j) {
            if (j + 1 < NJ4) {
                int kt1 = (j + 1) >> 2, c1 = (j + 1) & 3;
                afr[(j + 1) & 1] =
                    *(const bf16x8*)(w4base + ((size_t)((kt1 * 4 + c1) * 8 + wid) << 9));
            }
            int kt = j >> 2;
            int c16l = (j & 3) * 4 + quad;
#pragma unroll
            for (int lt = 0; lt < 4; ++lt) {
                int p = (lt * 16 + l15) * 2 + kt;   // h3 row <= 129
                int sc = (c16l & 8) | ((c16l & 7) ^ ((p >> 1) & 7));
                bf16x8 bfr = *(const bf16x8*)(h3 + p * 128 + sc * 8);
                acc[lt] = __builtin_amdgcn_mfma_f32_16x16x32_bf16(afr[j & 1], bfr, acc[lt], 0, 0, 0);
            }
        }
        // epilogue -> z bf16 [l][o] (ESE=136), zeros l>=59
        const int o0 = wid * 16 + quad * 4;
        const f32x4 bv = *(const f32x4*)(b4 + o0);
#pragma unroll
        for (int lt = 0; lt < 4; ++lt) {
            const int l = lt * 16 + l15;
            bf16x4 pk;
#pragma unroll
            for (int r = 0; r < 4; ++r) {
                float v = acc[lt][r] + bv[r];
                pk[r] = (l < 59) ? (bf16)v : (bf16)0.f;
            }
            *(bf16x4*)(zmem + l * 136 + o0) = pk;
        }
    }
    __syncthreads();

    // ================= distances + Student-t assignment ===================
#pragma unroll 1
    for (int cp = 0; cp < 8; ++cp) {
        const int kc = cp * 8 + wid;
        const bf16* cr = cbp + (size_t)kc * 8192;
        float t = 0.f;
#pragma unroll
        for (int it = 0; it < 16; ++it) {
            int ci = it * 64 + lane;
            int l = ci >> 4;
            int g = ci & 15;
            bf16x8 cv = *(const bf16x8*)(cr + ci * 8);
            bf16x8 zv = *(const bf16x8*)(zmem + l * 136 + g * 8);
#pragma unroll
            for (int e = 0; e < 8; ++e) {
                float zf = (float)zv[e];
                t += zf * (zf - 2.f * (float)cv[e]);
            }
        }
#pragma unroll
        for (int o = 32; o > 0; o >>= 1) t += __shfl_xor(t, o);
        if (lane == 0) d2s[kc] = t + cc[kc];
    }
    __syncthreads();
    if (tid < 64) {
        float q = 1.f / (1.f + d2s[tid]);  // ALPHA=1, exponent (ALPHA+1)/2 == 1
        float tot = q;
#pragma unroll
        for (int o = 32; o > 0; o >>= 1) tot += __shfl_xor(tot, o);
        out[n * 64 + tid] = q / tot;
    }
}

// ---------------- launcher ----------------
extern "C" void kernel_launch(void* const* d_in, const int* in_sizes, int n_in,
                              void* d_out, int out_size, void* d_ws, size_t ws_size,
                              hipStream_t stream) {
    (void)in_sizes; (void)n_in; (void)out_size; (void)ws_size;
    const float* x   = (const float*)d_in[0];
    const float* w1  = (const float*)d_in[1];
    const float* b1  = (const float*)d_in[2];
    const float* w2  = (const float*)d_in[3];
    const float* b2  = (const float*)d_in[4];
    const float* w3  = (const float*)d_in[5];
    const float* b3  = (const float*)d_in[6];
    const float* w4  = (const float*)d_in[7];
    const float* b4  = (const float*)d_in[8];
    const float* cen = (const float*)d_in[9];
    float* out = (float*)d_out;

    char* ws = (char*)d_ws;
    size_t off = 0;
    auto alloc = [&](size_t bytes) -> void* {
        void* p = ws + off;
        off += (bytes + 255) & ~(size_t)255;
        return p;
    };
    bf16* wT1 = (bf16*)alloc((size_t)15 * 16384 * sizeof(bf16));
    bf16* wT2 = (bf16*)alloc((size_t)12 * 16384 * sizeof(bf16));
    bf16* wT3 = (bf16*)alloc((size_t)7 * 16384 * sizeof(bf16));
    bf16* wT4 = (bf16*)alloc((size_t)4 * 16384 * sizeof(bf16));
    bf16* cbp = (bf16*)alloc((size_t)64 * 64 * 128 * sizeof(bf16));
    float* cc = (float*)alloc(64 * sizeof(float));
    bf16* h1  = (bf16*)alloc((size_t)256 * 512 * 128 * sizeof(bf16));
    (void)alloc((size_t)1 << 20);  // slack: tile overreads stay in-bounds

    // prep: 2432 wall blocks + 64 center blocks in one dispatch
    k_prep_all<<<2432 + 64, 256, 0, stream>>>(w1, w2, w3, w4, cen,
                                              wT1, wT2, wT3, wT4, cbp, cc);
    // conv1 (fused transpose): x 1024 -> 505(512 rows) K=15, LeakyReLU
    k_conv1<<<dim3(4, 256), 256, 0, stream>>>(x, wT1, b1, h1);
    // conv2+conv3+conv4+dist fused: one block per n, everything in LDS
    k_fused234<<<256, 512, 0, stream>>>(h1, wT2, wT3, wT4, b2, b3, b4, cbp, cc, out);
}